// Round 7
// baseline (64.277 us; speedup 1.0000x reference)
//
#include <hip/hip_runtime.h>

typedef unsigned short u16;
typedef unsigned int   u32;
typedef __attribute__((ext_vector_type(8))) short short8;
typedef __attribute__((ext_vector_type(4))) float f32x4;

__device__ __forceinline__ u16 f2bf(float f) {
    u32 u = __float_as_uint(f);
    u = (u + 0x7fffu + ((u >> 16) & 1u)) >> 16;
    return (u16)u;
}

__device__ __forceinline__ void gld_lds16(const void* g, void* l) {
    __builtin_amdgcn_global_load_lds(
        (const __attribute__((address_space(1))) u32*)g,
        (__attribute__((address_space(3))) u32*)l, 16, 0, 0);
}

// A-matrices stored fragment-major: A'[r>>4][k>>3][r&15][k&7]  dims [64][128][16][8]
__device__ __forceinline__ int ridx(int r, int k) {
    return ((((r >> 4) << 7) + (k >> 3)) << 7) + ((r & 15) << 3) + (k & 7);
}

// ---------------------------------------------------------------------------
// prep: 2818 blocks, every path LDS-tiled with coalesced 16B writes.
//   [0,768)      adj|wct cast+RETILE -> Ab|W0b|W1b
//   [768,1280)   wct transpose+cast+RETILE -> W0T|W1T
//   [1280,2816)  x transpose+cast -> Xt (linear)
//   [2816,2818)  W transpose+cast -> Wt (linear)
// ---------------------------------------------------------------------------
__global__ __launch_bounds__(256) void prep_kernel(
    const float* __restrict__ x, const float* __restrict__ adj,
    const float* __restrict__ wct, const float* __restrict__ W,
    u16* __restrict__ Ab, u16* __restrict__ W0T, u16* __restrict__ W1T,
    u16* __restrict__ Xt, u16* __restrict__ Wt)
{
    __shared__ float tile[64][65];
    const int t = threadIdx.x;
    const int bid = blockIdx.x;

    const float* src; u16* dst; int C, r0, c0, mode; int R = 0;
    if (bid < 768) {
        const int m = bid >> 8, q = bid & 255;
        src = (m == 0) ? adj : wct + (size_t)(m - 1) * 1048576;
        dst = Ab + m * 1048576;
        C = 1024; r0 = (q & 15) << 6; c0 = (q >> 4) << 6; mode = 0;
    } else if (bid < 1280) {
        const int mm = (bid - 768) >> 8, q = (bid - 768) & 255;
        src = wct + (size_t)mm * 1048576;
        dst = mm ? W1T : W0T;
        C = 1024; r0 = (q & 15) << 6; c0 = (q >> 4) << 6; mode = 1;
    } else if (bid < 2816) {
        const int q = bid - 1280;
        src = x; dst = Xt; C = 2048; R = 3072;
        r0 = (q % 48) << 6; c0 = (q / 48) << 6; mode = 2;
    } else {
        const int q = bid - 2816;
        src = W; dst = Wt; C = 128; R = 64;
        r0 = 0; c0 = q << 6; mode = 2;
    }

#pragma unroll
    for (int it = 0; it < 4; ++it) {
        const int f4 = it * 256 + t;
        const int r  = f4 >> 4;
        const int c4 = (f4 & 15) << 2;
        const float4 v = *(const float4*)&src[(size_t)(r0 + r) * C + c0 + c4];
        tile[r][c4]     = v.x; tile[r][c4 + 1] = v.y;
        tile[r][c4 + 2] = v.z; tile[r][c4 + 3] = v.w;
    }
    __syncthreads();

    if (mode == 0) {
        // no transpose, fragment-retile; consecutive t -> contiguous 16B
#pragma unroll
        for (int it = 0; it < 2; ++it) {
            const int g = it * 256 + t;
            const int r_lo = g & 15, fragk = (g >> 4) & 7, fragr = g >> 7;
            const int fi = (((r0 >> 4) + fragr) << 7) + (c0 >> 3) + fragk;
            const int rr = (fragr << 4) + r_lo, kk = fragk << 3;
            ushort4 o0, o1;
            o0.x = f2bf(tile[rr][kk]);     o0.y = f2bf(tile[rr][kk + 1]);
            o0.z = f2bf(tile[rr][kk + 2]); o0.w = f2bf(tile[rr][kk + 3]);
            o1.x = f2bf(tile[rr][kk + 4]); o1.y = f2bf(tile[rr][kk + 5]);
            o1.z = f2bf(tile[rr][kk + 6]); o1.w = f2bf(tile[rr][kk + 7]);
            *(ushort4*)&dst[(fi << 7) + (r_lo << 3)]     = o0;
            *(ushort4*)&dst[(fi << 7) + (r_lo << 3) + 4] = o1;
        }
    } else if (mode == 1) {
        // transpose + fragment-retile
#pragma unroll
        for (int it = 0; it < 2; ++it) {
            const int g = it * 256 + t;
            const int u_lo = g & 15, fragv = (g >> 4) & 7, fragu = g >> 7;
            const int fi = (((c0 >> 4) + fragu) << 7) + (r0 >> 3) + fragv;
            const int uu = (fragu << 4) + u_lo, vv = fragv << 3;
            ushort4 o0, o1;
            o0.x = f2bf(tile[vv][uu]);     o0.y = f2bf(tile[vv + 1][uu]);
            o0.z = f2bf(tile[vv + 2][uu]); o0.w = f2bf(tile[vv + 3][uu]);
            o1.x = f2bf(tile[vv + 4][uu]); o1.y = f2bf(tile[vv + 5][uu]);
            o1.z = f2bf(tile[vv + 6][uu]); o1.w = f2bf(tile[vv + 7][uu]);
            *(ushort4*)&dst[(fi << 7) + (u_lo << 3)]     = o0;
            *(ushort4*)&dst[(fi << 7) + (u_lo << 3) + 4] = o1;
        }
    } else {
        // plain transpose, linear dst
#pragma unroll
        for (int it = 0; it < 4; ++it) {
            const int f4 = it * 256 + t;
            const int u  = f4 >> 4;
            const int v4 = (f4 & 15) << 2;
            ushort4 o;
            o.x = f2bf(tile[v4][u]);     o.y = f2bf(tile[v4 + 1][u]);
            o.z = f2bf(tile[v4 + 2][u]); o.w = f2bf(tile[v4 + 3][u]);
            *(ushort4*)&dst[(size_t)(c0 + u) * R + r0 + v4] = o;
        }
    }
}

// ---------------------------------------------------------------------------
// gemm+glu fused. Block 128Mx64N, K_STEP=128, 4 waves 4Mx1N (wave 32x64).
// 56 barrier-pairs total (halved); 32 MFMA per pair per wave.
// A: direct L2->VGPR (retiled), prefetched 1 step; B: LDS dbuf 2x16KB,
// 16-slot XOR swizzle; counted vmcnt(12). 768 blocks = 3/CU balanced.
// ---------------------------------------------------------------------------
__global__ __launch_bounds__(256, 3) void gemm_h_kernel(
    const u16* __restrict__ Ab,  const u16* __restrict__ W0b,
    const u16* __restrict__ W1b, const u16* __restrict__ W0T,
    const u16* __restrict__ W1T, const u16* __restrict__ Xt,
    const u16* __restrict__ Wt,  const float* __restrict__ bias,
    float* __restrict__ out)
{
    __shared__ u16 Bdb[16384];    // 2 x 8192 elems (32 KB); epilogue: Hsm
    __shared__ u16 Wsm[8192];     // [c 128][cin 64] slot-swizzled (16 KB)
    __shared__ float Bias_sm[128];

    const int tid = threadIdx.x;
    const int bid = blockIdx.x;
    const int xcd = bid & 7;
    const int idx = bid >> 3;
    const int i   = idx >> 5;              // block-row 0..2 (dispatch round)
    const int idp = idx & 31;
    const int nt   = (xcd << 2) + (idp & 3);
    const int row0 = (idp >> 2) << 7;

    const int l    = tid & 63;
    const int w    = tid >> 6;
    const int lrow = l & 15;
    const int g16  = l >> 4;

    // ---- stage Wsm (pre-swizzled src, 8-slot) + bias
    {
        u16* wdst = Wsm + (w << 9);
#pragma unroll
        for (int p = 0; p < 4; ++p) {
            const int flat = p * 256 + tid;
            const int row = flat >> 3, slot = flat & 7;
            gld_lds16(Wt + row * 64 + ((slot ^ (row & 7)) << 3), wdst + p * 2048);
        }
        if (tid < 128) Bias_sm[tid] = bias[tid];
    }

    // ---- B staging: [col 64][k 128], 16-slot swizzle s_phys = s_log^(col&15)
    auto stageB = [&](u16* buf, const u16* tb, int k0) {
#pragma unroll
        for (int p = 0; p < 4; ++p) {
            const int col  = (w << 4) + (p << 2) + g16;
            const int slog = lrow ^ (col & 15);
            gld_lds16(tb + (size_t)col * 3072 + k0 + (slog << 3),
                      buf + (w << 11) + (p << 9));
        }
    };

    // ---- A direct loads (retiled): wave w rows [row0+w*32, +32)
    const int rbw = w << 1;
    auto loadA8 = [&](short8* d, const u16* ta, int k0) {
        const u16* base = ta + (((rbw << 7) + (k0 >> 3)) << 7) + (l << 3);
#pragma unroll
        for (int kk = 0; kk < 4; ++kk) {
            d[kk]     = *(const short8*)(base + (kk << 9));
            d[kk + 4] = *(const short8*)(base + 16384 + (kk << 9));
        }
    };

    f32x4 acc[2][4] = {};
    short8 aC[8], aN[8];

    const size_t xbase = (size_t)nt * 64 * 3072;
    const u16 *ca, *cb, *na, *nb, *fa = nullptr, *fb = nullptr;
    int nterms;
    if (i == 0) {
        ca = Ab  + (row0 << 10); cb = Xt + xbase;
        na = W0b + (row0 << 10); nb = Xt + xbase + 1024;
        nterms = 2;
    } else if (i == 1) {
        ca = W0T + (row0 << 10); cb = Xt + xbase;
        na = Ab  + (row0 << 10); nb = Xt + xbase + 1024;
        fa = W1b + (row0 << 10); fb = Xt + xbase + 2048;
        nterms = 3;
    } else {
        ca = W1T + (row0 << 10); cb = Xt + xbase + 1024;
        na = Ab  + (row0 << 10); nb = Xt + xbase + 2048;
        nterms = 2;
    }

    stageB(Bdb, cb, 0);
    loadA8(aC, ca, 0);

    for (int t = 0; t < nterms; ++t) {
#pragma unroll
        for (int k = 0; k < 8; ++k) {
            u16* bufc = Bdb + ((k & 1) << 13);
            u16* bufp = Bdb + (((k + 1) & 1) << 13);
            const u16* pa = (k < 7) ? ca : na;
            const u16* pb = (k < 7) ? cb : nb;
            const int pk0 = (k < 7) ? ((k + 1) << 7) : 0;
            const bool pf = (k < 7) || (na != nullptr);

            __builtin_amdgcn_s_barrier();               // done reading bufp
            if (pf) {
                stageB(bufp, pb, pk0);
                loadA8(aN, pa, pk0);
                asm volatile("s_waitcnt vmcnt(12)" ::: "memory");
            } else {
                asm volatile("s_waitcnt vmcnt(0)" ::: "memory");
            }
            __builtin_amdgcn_s_barrier();               // bufc globally ready

            __builtin_amdgcn_s_setprio(1);
#pragma unroll
            for (int kk = 0; kk < 4; ++kk) {
                const int so  = ((kk << 2) + g16) ^ lrow;
                const int cb0 = (lrow << 7) + (so << 3);
                const short8 b0 = *(const short8*)&bufc[cb0];
                const short8 b1 = *(const short8*)&bufc[cb0 + 2048];
                const short8 b2 = *(const short8*)&bufc[cb0 + 4096];
                const short8 b3 = *(const short8*)&bufc[cb0 + 6144];
                acc[0][0] = __builtin_amdgcn_mfma_f32_16x16x32_bf16(aC[kk],     b0, acc[0][0], 0, 0, 0);
                acc[0][1] = __builtin_amdgcn_mfma_f32_16x16x32_bf16(aC[kk],     b1, acc[0][1], 0, 0, 0);
                acc[0][2] = __builtin_amdgcn_mfma_f32_16x16x32_bf16(aC[kk],     b2, acc[0][2], 0, 0, 0);
                acc[0][3] = __builtin_amdgcn_mfma_f32_16x16x32_bf16(aC[kk],     b3, acc[0][3], 0, 0, 0);
                acc[1][0] = __builtin_amdgcn_mfma_f32_16x16x32_bf16(aC[kk + 4], b0, acc[1][0], 0, 0, 0);
                acc[1][1] = __builtin_amdgcn_mfma_f32_16x16x32_bf16(aC[kk + 4], b1, acc[1][1], 0, 0, 0);
                acc[1][2] = __builtin_amdgcn_mfma_f32_16x16x32_bf16(aC[kk + 4], b2, acc[1][2], 0, 0, 0);
                acc[1][3] = __builtin_amdgcn_mfma_f32_16x16x32_bf16(aC[kk + 4], b3, acc[1][3], 0, 0, 0);
            }
            __builtin_amdgcn_s_setprio(0);
#pragma unroll
            for (int j = 0; j < 8; ++j) aC[j] = aN[j];
        }
        ca = na; cb = nb; na = fa; nb = fb; fa = nullptr; fb = nullptr;
    }

    // ---- epilogue: Hsm <- bf16(acc) (swizzled, into Bdb), then GLU(H@W+b)
    __syncthreads();
    u16* Hsm = Bdb;   // [n 128][cin 64], 8-slot swizzle
#pragma unroll
    for (int fm = 0; fm < 2; ++fm)
#pragma unroll
        for (int fn = 0; fn < 4; ++fn)
#pragma unroll
            for (int r = 0; r < 4; ++r) {
                const int n   = (w << 5) + (fm << 4) + (g16 << 2) + r;
                const int cin = (fn << 4) + lrow;
                Hsm[(n << 6) + (((cin >> 3) ^ (n & 7)) << 3) + (cin & 7)] = f2bf(acc[fm][fn][r]);
            }

    // second GEMM: wave w -> out rows n = w*32..+31, all 128 W-cols
    f32x4 acc2[2][8];
#pragma unroll
    for (int fm2 = 0; fm2 < 2; ++fm2)
#pragma unroll
        for (int fn = 0; fn < 8; ++fn) {
            const float bv = Bias_sm[(fn << 4) + lrow];
            acc2[fm2][fn] = (f32x4){bv, bv, bv, bv};
        }
#pragma unroll
    for (int kk = 0; kk < 2; ++kk) {
        const int gg = (kk << 2) | g16;
        short8 ah[2], bw[8];
#pragma unroll
        for (int fm2 = 0; fm2 < 2; ++fm2) {
            const int n = (w << 5) + (fm2 << 4) + lrow;
            ah[fm2] = *(const short8*)&Hsm[(n << 6) + ((gg ^ (n & 7)) << 3)];
        }
#pragma unroll
        for (int fn = 0; fn < 8; ++fn) {
            const int c = (fn << 4) + lrow;
            bw[fn] = *(const short8*)&Wsm[(c << 6) + ((gg ^ (c & 7)) << 3)];
        }
#pragma unroll
        for (int fm2 = 0; fm2 < 2; ++fm2)
#pragma unroll
            for (int fn = 0; fn < 8; ++fn)
                acc2[fm2][fn] = __builtin_amdgcn_mfma_f32_16x16x32_bf16(
                    ah[fm2], bw[fn], acc2[fm2][fn], 0, 0, 0);
    }

    const int n0g = (i << 10) + row0;
#pragma unroll
    for (int fm2 = 0; fm2 < 2; ++fm2)
#pragma unroll
        for (int fn = 0; fn < 4; ++fn)
#pragma unroll
            for (int r = 0; r < 4; ++r) {
                const int nl = (w << 5) + (fm2 << 4) + (g16 << 2) + r;
                const float lhs = acc2[fm2][fn][r];
                const float rhs = acc2[fm2][fn + 4][r];
                const float sg  = 1.0f / (1.0f + __expf(-rhs));
                const int c = (fn << 4) + lrow;
                out[((size_t)(n0g + nl) * 32 + nt) * 64 + c] = lhs * sg;
            }
}

// ---------------------------------------------------------------------------
extern "C" void kernel_launch(void* const* d_in, const int* in_sizes, int n_in,
                              void* d_out, int out_size, void* d_ws, size_t ws_size,
                              hipStream_t stream)
{
    const float* x    = (const float*)d_in[0];   // (3072, 32, 64)
    const float* adj  = (const float*)d_in[1];   // (1024, 1024)
    const float* wct  = (const float*)d_in[2];   // (2, 1024, 1024)
    const float* W    = (const float*)d_in[3];   // (64, 128)
    const float* bias = (const float*)d_in[4];   // (128,)
    float* out = (float*)d_out;

    char* ws = (char*)d_ws;
    u16* Xt  = (u16*)ws;                    // bf16 [2048][3072] linear
    u16* Ab  = (u16*)(ws + 12582912);       // 3 x 1M bf16, RETILED (Ab|W0b|W1b)
    u16* W0b = Ab + 1048576;
    u16* W1b = Ab + 2097152;
    u16* W0T = (u16*)(ws + 18874368);       // 2 x 1M bf16, RETILED
    u16* W1T = W0T + 1048576;
    u16* Wt  = (u16*)(ws + 23068672);       // bf16 [128][64] linear

    prep_kernel<<<2818, 256, 0, stream>>>(x, adj, wct, W, Ab, W0T, W1T, Xt, Wt);
    gemm_h_kernel<<<768, 256, 0, stream>>>(Ab, W0b, W1b, W0T, W1T, Xt, Wt, bias, out);
}